// Round 2
// baseline (393.393 us; speedup 1.0000x reference)
//
#include <hip/hip_runtime.h>

#define HH 256
#define WW 256
#define CC 96
#define BB 8

#define TLH 32
#define TLW 64
#define XSH 40
#define XSW 72
#define HSH 40
#define HSW 68

__device__ __forceinline__ float silu_of(float z) {
    return z / (1.0f + __expf(-z));
}

__global__ __launch_bounds__(256, 4)
void trifreq_kernel(const float* __restrict__ x,
                    const float* __restrict__ w_lo,
                    const float* __restrict__ w_mf,
                    const float* __restrict__ w_hf,
                    const float* __restrict__ gamma,
                    const float* __restrict__ beta,
                    const float* __restrict__ mean,
                    const float* __restrict__ var,
                    float* __restrict__ out)
{
    __shared__ __align__(16) float xs[XSH * XSW];
    __shared__ __align__(16) float hsA[HSH * HSW];  // hs3, later reused as bp/hp tile
    __shared__ __align__(16) float hs7[HSH * HSW];
    __shared__ float rc[4 * HSW];

    const int tid = threadIdx.x;
    const int tileIdx = blockIdx.x;
    const int c = blockIdx.y;
    const int b = blockIdx.z;
    const int th = (tileIdx >> 2) * TLH;
    const int tw = (tileIdx & 3) * TLW;

    const int g  = c >> 5;
    const int ci = c & 31;
    const int c_out = ci * 3 + g;

    const float* __restrict__ xin = x + (size_t)(b * CC + c) * (size_t)(HH * WW);

    for (int i = tid; i < 4 * HSW; i += 256) {
        const int tbl = i / HSW;
        const int k   = i - tbl * HSW;
        const int pos = ((tbl < 2) ? th : tw) + (k - 1);
        const int rad = (tbl & 1) ? 3 : 1;
        const int cnt = min(pos + rad, HH - 1) - max(pos - rad, 0) + 1;
        rc[i] = (pos >= 0 && pos < HH) ? (1.0f / (float)cnt) : 0.0f;
    }

    for (int idx = tid; idx < XSH * 18; idx += 256) {
        const int r  = idx / 18;
        const int c4 = (idx - r * 18) * 4;
        const int gh = th - 4 + r;
        const int gw = tw - 4 + c4;
        float4 v = make_float4(0.f, 0.f, 0.f, 0.f);
        if ((unsigned)gh < (unsigned)HH && (unsigned)gw <= (unsigned)(WW - 4))
            v = *reinterpret_cast<const float4*>(xin + (size_t)gh * WW + gw);
        *reinterpret_cast<float4*>(&xs[r * XSW + c4]) = v;
    }
    __syncthreads();

    const int qr = (tid >> 4) * 2;
    const int qc = (tid & 15) * 4;
    float acc0[4] = {0.f, 0.f, 0.f, 0.f};
    float acc1[4] = {0.f, 0.f, 0.f, 0.f};

    if (g == 0) {
        const float* __restrict__ wp = w_lo + ci * 25;
        float wk[25];
        #pragma unroll
        for (int t = 0; t < 25; ++t) wk[t] = wp[t];
        #pragma unroll
        for (int rr = 0; rr < 6; ++rr) {
            const float* row = &xs[(qr + rr + 2) * XSW + (qc + 2)];
            float v[8];
            #pragma unroll
            for (int j = 0; j < 8; ++j) v[j] = row[j];
            if (rr < 5) {
                const float* wr = &wk[rr * 5];
                #pragma unroll
                for (int j = 0; j < 4; ++j)
                    acc0[j] += v[j]*wr[0] + v[j+1]*wr[1] + v[j+2]*wr[2] + v[j+3]*wr[3] + v[j+4]*wr[4];
            }
            if (rr >= 1) {
                const float* wr = &wk[(rr - 1) * 5];
                #pragma unroll
                for (int j = 0; j < 4; ++j)
                    acc1[j] += v[j]*wr[0] + v[j+1]*wr[1] + v[j+2]*wr[2] + v[j+3]*wr[3] + v[j+4]*wr[4];
            }
        }
    } else {
        for (int t = tid; t < HSH * 11; t += 256) {
            const int r   = t / 11;
            const int ci0 = (t - r * 11) * 6;
            const float* row = &xs[r * XSW + ci0];
            float v[12];
            #pragma unroll
            for (int j = 0; j < 12; ++j) v[j] = row[j];
            float s7 = v[0]+v[1]+v[2]+v[3]+v[4]+v[5]+v[6];
            float s3 = v[2]+v[3]+v[4];
            float* p7 = &hs7[r * HSW + ci0];
            float* p3 = &hsA[r * HSW + ci0];
            #pragma unroll
            for (int j = 0; j < 6; ++j) {
                p7[j] = s7;
                p3[j] = s3;
                if (j < 5) { s7 += v[j+7] - v[j]; s3 += v[j+5] - v[j+2]; }
            }
        }
        __syncthreads();

        float res[3][4];
        if (g == 1) {
            int nt = 0;
            for (int t = tid; t < 34 * 17; t += 256, ++nt) {
                const int r   = t / 17;
                const int ci0 = (t - r * 17) * 4;
                float a7x=0.f, a7y=0.f, a7z=0.f, a7w=0.f;
                #pragma unroll
                for (int d = 0; d < 7; ++d) {
                    const float4 h = *reinterpret_cast<const float4*>(&hs7[(r + d) * HSW + ci0]);
                    a7x += h.x; a7y += h.y; a7z += h.z; a7w += h.w;
                }
                float a3x=0.f, a3y=0.f, a3z=0.f, a3w=0.f;
                #pragma unroll
                for (int d = 2; d < 5; ++d) {
                    const float4 h = *reinterpret_cast<const float4*>(&hsA[(r + d) * HSW + ci0]);
                    a3x += h.x; a3y += h.y; a3z += h.z; a3w += h.w;
                }
                const float f3 = rc[r];
                const float f7 = rc[HSW + r];
                res[nt][0] = a3x * (f3 * rc[2*HSW + ci0 + 0]) - a7x * (f7 * rc[3*HSW + ci0 + 0]);
                res[nt][1] = a3y * (f3 * rc[2*HSW + ci0 + 1]) - a7y * (f7 * rc[3*HSW + ci0 + 1]);
                res[nt][2] = a3z * (f3 * rc[2*HSW + ci0 + 2]) - a7z * (f7 * rc[3*HSW + ci0 + 2]);
                res[nt][3] = a3w * (f3 * rc[2*HSW + ci0 + 3]) - a7w * (f7 * rc[3*HSW + ci0 + 3]);
            }
        } else {
            int nt = 0;
            for (int t = tid; t < 34 * 17; t += 256, ++nt) {
                const int r   = t / 17;
                const int ci0 = (t - r * 17) * 4;
                float a3x=0.f, a3y=0.f, a3z=0.f, a3w=0.f;
                #pragma unroll
                for (int d = 2; d < 5; ++d) {
                    const float4 h = *reinterpret_cast<const float4*>(&hsA[(r + d) * HSW + ci0]);
                    a3x += h.x; a3y += h.y; a3z += h.z; a3w += h.w;
                }
                const float f3 = rc[r];
                const float* xr = &xs[(r + 3) * XSW + (ci0 + 3)];
                res[nt][0] = xr[0] - a3x * (f3 * rc[2*HSW + ci0 + 0]);
                res[nt][1] = xr[1] - a3y * (f3 * rc[2*HSW + ci0 + 1]);
                res[nt][2] = xr[2] - a3z * (f3 * rc[2*HSW + ci0 + 2]);
                res[nt][3] = xr[3] - a3w * (f3 * rc[2*HSW + ci0 + 3]);
            }
        }
        __syncthreads();
        {
            int nt = 0;
            for (int t = tid; t < 34 * 17; t += 256, ++nt) {
                const int r   = t / 17;
                const int ci0 = (t - r * 17) * 4;
                *reinterpret_cast<float4*>(&hsA[r * HSW + ci0]) =
                    make_float4(res[nt][0], res[nt][1], res[nt][2], res[nt][3]);
            }
        }
        __syncthreads();

        const float* __restrict__ wp = ((g == 1) ? w_mf : w_hf) + ci * 9;
        float wk[9];
        #pragma unroll
        for (int t = 0; t < 9; ++t) wk[t] = wp[t];
        #pragma unroll
        for (int rr = 0; rr < 4; ++rr) {
            const float* row = &hsA[(qr + rr) * HSW + qc];
            float v[6];
            #pragma unroll
            for (int j = 0; j < 6; ++j) v[j] = row[j];
            if (rr < 3) {
                const float* wr = &wk[rr * 3];
                #pragma unroll
                for (int j = 0; j < 4; ++j)
                    acc0[j] += v[j]*wr[0] + v[j+1]*wr[1] + v[j+2]*wr[2];
            }
            if (rr >= 1) {
                const float* wr = &wk[(rr - 1) * 3];
                #pragma unroll
                for (int j = 0; j < 4; ++j)
                    acc1[j] += v[j]*wr[0] + v[j+1]*wr[1] + v[j+2]*wr[2];
            }
        }
    }

    const float bninv  = gamma[c_out] * rsqrtf(var[c_out] + 1e-5f);
    const float bnbias = beta[c_out] - mean[c_out] * bninv;
    float* __restrict__ op = out + ((size_t)(b * CC + c_out) * HH + (th + qr)) * (size_t)WW + (tw + qc);
    float4 o0, o1;
    o0.x = silu_of(acc0[0] * bninv + bnbias);
    o0.y = silu_of(acc0[1] * bninv + bnbias);
    o0.z = silu_of(acc0[2] * bninv + bnbias);
    o0.w = silu_of(acc0[3] * bninv + bnbias);
    o1.x = silu_of(acc1[0] * bninv + bnbias);
    o1.y = silu_of(acc1[1] * bninv + bnbias);
    o1.z = silu_of(acc1[2] * bninv + bnbias);
    o1.w = silu_of(acc1[3] * bninv + bnbias);
    *reinterpret_cast<float4*>(op) = o0;
    *reinterpret_cast<float4*>(op + WW) = o1;
}

extern "C" void kernel_launch(void* const* d_in, const int* in_sizes, int n_in,
                              void* d_out, int out_size, void* d_ws, size_t ws_size,
                              hipStream_t stream) {
    const float* x    = (const float*)d_in[0];
    const float* w_lo = (const float*)d_in[1];
    const float* w_mf = (const float*)d_in[2];
    const float* w_hf = (const float*)d_in[3];
    const float* gam  = (const float*)d_in[4];
    const float* bet  = (const float*)d_in[5];
    const float* mea  = (const float*)d_in[6];
    const float* va   = (const float*)d_in[7];
    float* out = (float*)d_out;

    dim3 grid(32, CC, BB);
    dim3 block(256);
    hipLaunchKernelGGL(trifreq_kernel, grid, block, 0, stream,
                       x, w_lo, w_mf, w_hf, gam, bet, mea, va, out);
}